// Round 1
// baseline (455.760 us; speedup 1.0000x reference)
//
#include <hip/hip_runtime.h>

// Problem constants (B,O,I,D_out,D_in) = (512,10,1152,16,8)
#define BB 512
#define OO 10
#define II 1152
#define DD 16
#define EE 8
#define GB 16            // batches per block
#define IC 16            // i-chunks across blocks
#define ILEN (II / IC)   // 72 i's per chunk
#define NBLK ((BB / GB) * IC)  // 512 blocks

// Butterfly sum across the 16-lane d-group (d = lane&15). All lanes get the sum.
__device__ __forceinline__ float dred16(float v) {
    v += __shfl_xor(v, 1);
    v += __shfl_xor(v, 2);
    v += __shfl_xor(v, 4);
    v += __shfl_xor(v, 8);
    return v;
}

// One routing pass. PASS=0: uniform c=0.1 -> s0. PASS=1: b=<v0,xh> -> softmax -> s1.
// PASS=2: b=<v0+v1,xh> -> softmax -> s2.
template <int PASS>
__global__ __launch_bounds__(256, 2)
void caps_pass(const float* __restrict__ x, const float* __restrict__ W,
               float* __restrict__ s_out,
               const float* __restrict__ s0, const float* __restrict__ s1) {
    // x tile for this block's 16 batches x 72 i's: [16][72][8] floats = 36 KB
    __shared__ float4 xlds[GB * ILEN * 2];

    const int tid = threadIdx.x;
    const int d = tid & 15;       // output-capsule dim lane
    const int g = tid >> 4;       // local batch 0..15
    const int bg = blockIdx.x >> 4;
    const int ic = blockIdx.x & 15;
    const int b = bg * GB + g;
    const int i0 = ic * ILEN;

    // Cooperative coalesced stage of x[bg*16 .. +15][i0 .. i0+71][:] into LDS
    const float4* x4 = (const float4*)x;
    #pragma unroll
    for (int k = tid; k < GB * ILEN * 2; k += 256) {
        const int gg = k / (ILEN * 2);
        const int rem = k - gg * (ILEN * 2);
        xlds[k] = x4[(size_t)(bg * GB + gg) * (II * EE / 4) + (size_t)i0 * 2 + rem];
    }

    // Per-thread v[o] = squash(s0)[b,o,d] (+ squash(s1)[b,o,d] for PASS 2).
    float vreg[OO];
    if constexpr (PASS >= 1) {
        #pragma unroll
        for (int o = 0; o < OO; o++) {
            float sv = s0[(b * OO + o) * DD + d];
            float sn = dred16(sv * sv);
            float v = sv * (sn / ((1.0f + sn) * sqrtf(sn)));
            if constexpr (PASS == 2) {
                float sv1 = s1[(b * OO + o) * DD + d];
                float sn1 = dred16(sv1 * sv1);
                v += sv1 * (sn1 / ((1.0f + sn1) * sqrtf(sn1)));
            }
            vreg[o] = v;
        }
    }
    __syncthreads();

    float sacc[OO];
    #pragma unroll
    for (int o = 0; o < OO; o++) sacc[o] = 0.0f;

    const float4* W4 = (const float4*)W;
    for (int ii = 0; ii < ILEN; ii++) {
        const int i = i0 + ii;
        const float4 xa = xlds[(g * ILEN + ii) * 2 + 0];
        const float4 xb = xlds[(g * ILEN + ii) * 2 + 1];

        // xh[o] = x_hat[b,o,i,d] = sum_e W[o,i,d,e] * x[b,i,e]
        float xh[OO];
        #pragma unroll
        for (int o = 0; o < OO; o++) {
            const float4* wp = W4 + (size_t)(((o * II + i) * DD + d) * 2);
            const float4 wa = wp[0];
            const float4 wb = wp[1];
            float h = wa.x * xa.x;
            h = fmaf(wa.y, xa.y, h);
            h = fmaf(wa.z, xa.z, h);
            h = fmaf(wa.w, xa.w, h);
            h = fmaf(wb.x, xb.x, h);
            h = fmaf(wb.y, xb.y, h);
            h = fmaf(wb.z, xb.z, h);
            h = fmaf(wb.w, xb.w, h);
            xh[o] = h;
        }

        if constexpr (PASS == 0) {
            #pragma unroll
            for (int o = 0; o < OO; o++) sacc[o] += xh[o];
        } else {
            // b[o] = sum_d vreg[o]*xh[o]  (reduce across the 16 d-lanes)
            float bo[OO];
            #pragma unroll
            for (int o = 0; o < OO; o++) bo[o] = dred16(vreg[o] * xh[o]);
            // softmax over o (redundant across d-lanes, cheap)
            float m = bo[0];
            #pragma unroll
            for (int o = 1; o < OO; o++) m = fmaxf(m, bo[o]);
            float se = 0.0f;
            #pragma unroll
            for (int o = 0; o < OO; o++) { bo[o] = __expf(bo[o] - m); se += bo[o]; }
            const float inv = 1.0f / se;
            #pragma unroll
            for (int o = 0; o < OO; o++) sacc[o] = fmaf(bo[o] * inv, xh[o], sacc[o]);
        }
    }

    const float scale = (PASS == 0) ? 0.1f : 1.0f;
    #pragma unroll
    for (int o = 0; o < OO; o++)
        atomicAdd(&s_out[(b * OO + o) * DD + d], sacc[o] * scale);
}

// Finalize: outputs = squash(s2); idx = argmax_o ||outputs||; t = outputs[idx].
// d_out layout: t [B,1,16] flat first, then outputs [B,10,16].
__global__ __launch_bounds__(192)
void caps_final(const float* __restrict__ s2, float* __restrict__ out) {
    __shared__ float norml[12];
    const int b = blockIdx.x;
    const int tid = threadIdx.x;
    const int d = tid & 15;
    const int o = tid >> 4;  // 0..11, active o<10

    float v = 0.0f;
    if (o < OO) {
        const float sv = s2[(b * OO + o) * DD + d];
        const float sn = dred16(sv * sv);
        v = sv * (sn / ((1.0f + sn) * sqrtf(sn)));
        out[BB * DD + (b * OO + o) * DD + d] = v;
        if (d == 0) norml[o] = sn;  // argmax(softmax(sqrt(sn))) == argmax(sn)
    }
    __syncthreads();

    int idx = 0;
    float best = norml[0];
    #pragma unroll
    for (int oo = 1; oo < OO; oo++) {
        const float n = norml[oo];
        if (n > best) { best = n; idx = oo; }
    }
    if (o == idx) out[b * DD + d] = v;
}

extern "C" void kernel_launch(void* const* d_in, const int* in_sizes, int n_in,
                              void* d_out, int out_size, void* d_ws, size_t ws_size,
                              hipStream_t stream) {
    const float* x = (const float*)d_in[0];  // [512,1152,8]
    const float* W = (const float*)d_in[1];  // [10,1152,16,8]
    float* out = (float*)d_out;              // [512*16 t] ++ [512*10*16 outputs]

    float* s0 = (float*)d_ws;                // [512,10,16]
    float* s1 = s0 + BB * OO * DD;
    float* s2 = s1 + BB * OO * DD;

    hipMemsetAsync(d_ws, 0, (size_t)3 * BB * OO * DD * sizeof(float), stream);

    caps_pass<0><<<NBLK, 256, 0, stream>>>(x, W, s0, nullptr, nullptr);
    caps_pass<1><<<NBLK, 256, 0, stream>>>(x, W, s1, s0, nullptr);
    caps_pass<2><<<NBLK, 256, 0, stream>>>(x, W, s2, s0, s1);
    caps_final<<<BB, 192, 0, stream>>>(s2, out);
}

// Round 3
// 279.253 us; speedup vs baseline: 1.6321x; 1.6321x over previous
//
#include <hip/hip_runtime.h>

// Problem constants (B,O,I,D_out,D_in) = (512,10,1152,16,8)
#define BB 512
#define OO 10
#define II 1152
#define DD 16
#define EE 8
#define GB 16            // batches per block
#define IC 32            // i-chunks across blocks
#define ILEN (II / IC)   // 36 i's per chunk
#define NBLK ((BB / GB) * IC)  // 1024 blocks = 4/CU
#define XROW (ILEN * 2 + 1)    // padded LDS row stride (float4s) to break bank aliasing

// One DPP-shuffled add: v + dpp(v). Compiler inserts the required DPP hazard NOPs.
template <int CTRL>
__device__ __forceinline__ float dpp_add(float v) {
    int s = __builtin_amdgcn_update_dpp(0, __float_as_int(v), CTRL, 0xf, 0xf, true);
    return v + __int_as_float(s);
}

// Butterfly sum across the 16-lane d-group (d = lane&15), pure VALU via DPP.
// xor1 = quad_perm[1,0,3,2]=0xB1; xor2 = quad_perm[2,3,0,1]=0x4E;
// after 4-lane uniformity row_half_mirror(0x141) == xor4; then row_mirror(0x140) == xor8.
__device__ __forceinline__ float dred16(float v) {
    v = dpp_add<0xB1>(v);
    v = dpp_add<0x4E>(v);
    v = dpp_add<0x141>(v);
    v = dpp_add<0x140>(v);
    return v;
}

// One routing pass. PASS=0: uniform c=0.1 -> s0. PASS=1: b=<v0,xh> -> softmax -> s1.
// PASS=2: b=<v0+v1,xh> -> softmax -> s2.
template <int PASS>
__global__ __launch_bounds__(256, 4)
void caps_pass(const float* __restrict__ x, const float* __restrict__ W,
               float* __restrict__ s_out,
               const float* __restrict__ s0, const float* __restrict__ s1) {
    // x tile for this block's 16 batches x 36 i's: [16][36][8] floats, padded rows
    __shared__ float4 xlds[GB * XROW];

    const int tid = threadIdx.x;
    const int d = tid & 15;       // output-capsule dim lane
    const int g = tid >> 4;       // local batch 0..15
    const int bg = blockIdx.x >> 5;   // batch group (32 of them)
    const int ic = blockIdx.x & 31;   // i-chunk
    const int b = bg * GB + g;
    const int i0 = ic * ILEN;

    // Cooperative coalesced stage of x[bg*16 .. +15][i0 .. i0+35][:] into LDS
    const float4* x4 = (const float4*)x;
    for (int k = tid; k < GB * ILEN * 2; k += 256) {
        const int gg = k / (ILEN * 2);
        const int rem = k - gg * (ILEN * 2);
        xlds[gg * XROW + rem] =
            x4[(size_t)(bg * GB + gg) * (II * EE / 4) + (size_t)i0 * 2 + rem];
    }

    // Per-thread v[o] = squash(s0)[b,o,d] (+ squash(s1)[b,o,d] for PASS 2).
    float vreg[OO];
    if constexpr (PASS >= 1) {
        #pragma unroll
        for (int o = 0; o < OO; o++) {
            float sv = s0[(b * OO + o) * DD + d];
            float sn = dred16(sv * sv);
            float v = sv * (sn / ((1.0f + sn) * sqrtf(sn)));
            if constexpr (PASS == 2) {
                float sv1 = s1[(b * OO + o) * DD + d];
                float sn1 = dred16(sv1 * sv1);
                v += sv1 * (sn1 / ((1.0f + sn1) * sqrtf(sn1)));
            }
            vreg[o] = v;
        }
    }
    __syncthreads();

    float sacc[OO];
    #pragma unroll
    for (int o = 0; o < OO; o++) sacc[o] = 0.0f;

    const float4* W4 = (const float4*)W;
    for (int ii = 0; ii < ILEN; ii++) {
        const int i = i0 + ii;
        const float4 xa = xlds[g * XROW + ii * 2 + 0];
        const float4 xb = xlds[g * XROW + ii * 2 + 1];

        // xh[o] = x_hat[b,o,i,d] = sum_e W[o,i,d,e] * x[b,i,e]
        float xh[OO];
        #pragma unroll
        for (int o = 0; o < OO; o++) {
            const float4* wp = W4 + (size_t)(((o * II + i) * DD + d) * 2);
            const float4 wa = wp[0];
            const float4 wb = wp[1];
            float h = wa.x * xa.x;
            h = fmaf(wa.y, xa.y, h);
            h = fmaf(wa.z, xa.z, h);
            h = fmaf(wa.w, xa.w, h);
            h = fmaf(wb.x, xb.x, h);
            h = fmaf(wb.y, xb.y, h);
            h = fmaf(wb.z, xb.z, h);
            h = fmaf(wb.w, xb.w, h);
            xh[o] = h;
        }

        if constexpr (PASS == 0) {
            #pragma unroll
            for (int o = 0; o < OO; o++) sacc[o] += xh[o];
        } else {
            // b[o] = sum_d vreg[o]*xh[o]  (reduce across the 16 d-lanes, DPP)
            float bo[OO];
            #pragma unroll
            for (int o = 0; o < OO; o++) bo[o] = dred16(vreg[o] * xh[o]);
            // softmax over o; |bo| <= ~0.5 so the max-shift is unnecessary
            float se = 0.0f;
            #pragma unroll
            for (int o = 0; o < OO; o++) { bo[o] = __expf(bo[o]); se += bo[o]; }
            const float inv = 1.0f / se;
            #pragma unroll
            for (int o = 0; o < OO; o++) sacc[o] = fmaf(bo[o] * inv, xh[o], sacc[o]);
        }
    }

    const float scale = (PASS == 0) ? 0.1f : 1.0f;
    #pragma unroll
    for (int o = 0; o < OO; o++)
        atomicAdd(&s_out[(b * OO + o) * DD + d], sacc[o] * scale);
}

// Finalize: outputs = squash(s2); idx = argmax_o ||outputs||; t = outputs[idx].
// d_out layout: t [B,1,16] flat first, then outputs [B,10,16].
__global__ __launch_bounds__(192)
void caps_final(const float* __restrict__ s2, float* __restrict__ out) {
    __shared__ float norml[12];
    const int b = blockIdx.x;
    const int tid = threadIdx.x;
    const int d = tid & 15;
    const int o = tid >> 4;  // 0..11, active o<10

    float v = 0.0f;
    if (o < OO) {
        const float sv = s2[(b * OO + o) * DD + d];
        const float sn = dred16(sv * sv);
        v = sv * (sn / ((1.0f + sn) * sqrtf(sn)));
        out[BB * DD + (b * OO + o) * DD + d] = v;
        if (d == 0) norml[o] = sn;  // argmax(softmax(sqrt(sn))) == argmax(sn)
    }
    __syncthreads();

    int idx = 0;
    float best = norml[0];
    #pragma unroll
    for (int oo = 1; oo < OO; oo++) {
        const float n = norml[oo];
        if (n > best) { best = n; idx = oo; }
    }
    if (o == idx) out[b * DD + d] = v;
}

extern "C" void kernel_launch(void* const* d_in, const int* in_sizes, int n_in,
                              void* d_out, int out_size, void* d_ws, size_t ws_size,
                              hipStream_t stream) {
    const float* x = (const float*)d_in[0];  // [512,1152,8]
    const float* W = (const float*)d_in[1];  // [10,1152,16,8]
    float* out = (float*)d_out;              // [512*16 t] ++ [512*10*16 outputs]

    float* s0 = (float*)d_ws;                // [512,10,16]
    float* s1 = s0 + BB * OO * DD;
    float* s2 = s1 + BB * OO * DD;

    hipMemsetAsync(d_ws, 0, (size_t)3 * BB * OO * DD * sizeof(float), stream);

    caps_pass<0><<<NBLK, 256, 0, stream>>>(x, W, s0, nullptr, nullptr);
    caps_pass<1><<<NBLK, 256, 0, stream>>>(x, W, s1, s0, nullptr);
    caps_pass<2><<<NBLK, 256, 0, stream>>>(x, W, s2, s0, s1);
    caps_final<<<BB, 192, 0, stream>>>(s2, out);
}

// Round 4
// 248.180 us; speedup vs baseline: 1.8364x; 1.1252x over previous
//
#include <hip/hip_runtime.h>

// Problem constants (B,O,I,D_out,D_in) = (512,10,1152,16,8)
#define BB 512
#define OO 10
#define II 1152
#define DD 16
#define EE 8
#define GB 32            // batches per block: 16 g-threads x 2 b each
#define IC 64            // i-chunks across blocks
#define ILEN (II / IC)   // 18 i's per chunk
#define NBLK ((BB / GB) * IC)  // 16*64 = 1024 blocks = 4/CU
#define XROW (ILEN * 2 + 1)    // padded LDS row stride (float4s)
#define WSLAB (II * DD * EE / 4) // float4s per o-slab of W = 36864

typedef float v2f __attribute__((ext_vector_type(2)));
typedef float v4f __attribute__((ext_vector_type(4)));

// Packed fp32 math (VOP3P; plain VALU, no DPP hazards).
__device__ __forceinline__ v2f pk_mul(v2f a, v2f b) {
    v2f d;
    asm("v_pk_mul_f32 %0, %1, %2" : "=v"(d) : "v"(a), "v"(b));
    return d;
}
__device__ __forceinline__ v2f pk_fma(v2f a, v2f b, v2f c) {
    v2f d;
    asm("v_pk_fma_f32 %0, %1, %2, %3" : "=v"(d) : "v"(a), "v"(b), "v"(c));
    return d;
}

// 8-element dot: W row (2 float4) . x row (2 float4), via 1 pk_mul + 3 pk_fma + 1 add.
__device__ __forceinline__ float dot8(v4f wa, v4f wb, v4f xa, v4f xb) {
    v2f p = pk_mul(wa.lo, xa.lo);
    p = pk_fma(wa.hi, xa.hi, p);
    p = pk_fma(wb.lo, xb.lo, p);
    p = pk_fma(wb.hi, xb.hi, p);
    return p.x + p.y;
}

// One DPP-shuffled add; compiler inserts required DPP hazard NOPs.
template <int CTRL>
__device__ __forceinline__ float dpp_add(float v) {
    int s = __builtin_amdgcn_update_dpp(0, __float_as_int(v), CTRL, 0xf, 0xf, true);
    return v + __int_as_float(s);
}
// Butterfly sum across the 16-lane d-group (d = lane&15), pure VALU.
__device__ __forceinline__ float dred16(float v) {
    v = dpp_add<0xB1>(v);    // xor1 (quad_perm[1,0,3,2])
    v = dpp_add<0x4E>(v);    // xor2 (quad_perm[2,3,0,1])
    v = dpp_add<0x141>(v);   // row_half_mirror == xor4 after 4-lane uniformity
    v = dpp_add<0x140>(v);   // row_mirror == xor8 after 8-lane uniformity
    return v;
}

__device__ __forceinline__ float squash_lane(float sv) {
    float sn = dred16(sv * sv);
    return sv * (sn / ((1.0f + sn) * sqrtf(sn)));
}

// One routing pass. PASS=0: uniform c=0.1 -> s0. PASS=1: b=<v0,xh> -> softmax -> s1.
// PASS=2: b=<v0+v1,xh> -> softmax -> s2. Each thread owns 2 batches (b0, b0+16).
template <int PASS>
__global__ __launch_bounds__(256, 4)
void caps_pass(const float* __restrict__ x, const float* __restrict__ W,
               float* __restrict__ s_out,
               const float* __restrict__ s0, const float* __restrict__ s1) {
    __shared__ v4f xlds[GB * XROW];   // 32 batches x 18 i x 8 floats, padded rows

    const int tid = threadIdx.x;
    const int d = tid & 15;
    const int g = tid >> 4;           // 0..15
    const int bg = blockIdx.x >> 6;   // 16 batch groups
    const int ic = blockIdx.x & 63;   // 64 i-chunks
    const int b0 = bg * GB + g;
    const int b1 = b0 + 16;
    const int i0 = ic * ILEN;

    // Stage x[bg*32 .. +31][i0 .. i0+17][:] into LDS (coalesced float4)
    const v4f* x4 = (const v4f*)x;
    for (int k = tid; k < GB * ILEN * 2; k += 256) {
        const int gg = k / (ILEN * 2);
        const int rem = k - gg * (ILEN * 2);
        xlds[gg * XROW + rem] =
            x4[(size_t)(bg * GB + gg) * (II * EE / 4) + (size_t)i0 * 2 + rem];
    }

    constexpr float LOG2E = 1.44269504f;
    // vr = log2(e) * (squash(s0) [+ squash(s1)]) so softmax uses exp2 directly.
    float vr0[OO], vr1[OO];
    if constexpr (PASS >= 1) {
        #pragma unroll
        for (int o = 0; o < OO; o++) {
            float v = squash_lane(s0[(b0 * OO + o) * DD + d]);
            float w = squash_lane(s0[(b1 * OO + o) * DD + d]);
            if constexpr (PASS == 2) {
                v += squash_lane(s1[(b0 * OO + o) * DD + d]);
                w += squash_lane(s1[(b1 * OO + o) * DD + d]);
            }
            vr0[o] = v * LOG2E;
            vr1[o] = w * LOG2E;
        }
    }
    __syncthreads();

    float sa0[OO], sa1[OO];
    #pragma unroll
    for (int o = 0; o < OO; o++) { sa0[o] = 0.0f; sa1[o] = 0.0f; }

    const v4f* W4 = (const v4f*)W;
    int widx = (i0 * DD + d) * 2;   // float4 index inside an o-slab

    for (int ii = 0; ii < ILEN; ii++) {
        const v4f xa0 = xlds[g * XROW + ii * 2 + 0];
        const v4f xb0 = xlds[g * XROW + ii * 2 + 1];
        const v4f xa1 = xlds[(g + 16) * XROW + ii * 2 + 0];
        const v4f xb1 = xlds[(g + 16) * XROW + ii * 2 + 1];

        float xh0[OO], xh1[OO];
        #pragma unroll
        for (int o = 0; o < OO; o++) {
            const v4f wa = W4[o * WSLAB + widx];
            const v4f wb = W4[o * WSLAB + widx + 1];
            xh0[o] = dot8(wa, wb, xa0, xb0);  // W reused for both batches
            xh1[o] = dot8(wa, wb, xa1, xb1);
        }

        if constexpr (PASS == 0) {
            #pragma unroll
            for (int o = 0; o < OO; o++) { sa0[o] += xh0[o]; sa1[o] += xh1[o]; }
        } else {
            float e0[OO], e1[OO];
            float se0 = 0.0f, se1 = 0.0f;
            #pragma unroll
            for (int o = 0; o < OO; o++) {
                e0[o] = __builtin_amdgcn_exp2f(dred16(vr0[o] * xh0[o]));
                e1[o] = __builtin_amdgcn_exp2f(dred16(vr1[o] * xh1[o]));
                se0 += e0[o];
                se1 += e1[o];
            }
            const float inv0 = __builtin_amdgcn_rcpf(se0);
            const float inv1 = __builtin_amdgcn_rcpf(se1);
            #pragma unroll
            for (int o = 0; o < OO; o++) {
                sa0[o] = fmaf(e0[o] * inv0, xh0[o], sa0[o]);
                sa1[o] = fmaf(e1[o] * inv1, xh1[o], sa1[o]);
            }
        }
        widx += DD * 2;
    }

    const float scale = (PASS == 0) ? 0.1f : 1.0f;
    #pragma unroll
    for (int o = 0; o < OO; o++) {
        atomicAdd(&s_out[(b0 * OO + o) * DD + d], sa0[o] * scale);
        atomicAdd(&s_out[(b1 * OO + o) * DD + d], sa1[o] * scale);
    }
}

// Finalize: outputs = squash(s2); idx = argmax_o ||outputs||; t = outputs[idx].
// d_out layout: t [B,1,16] flat first, then outputs [B,10,16].
__global__ __launch_bounds__(192)
void caps_final(const float* __restrict__ s2, float* __restrict__ out) {
    __shared__ float norml[12];
    const int b = blockIdx.x;
    const int tid = threadIdx.x;
    const int d = tid & 15;
    const int o = tid >> 4;  // 0..11, active o<10

    float v = 0.0f;
    if (o < OO) {
        const float sv = s2[(b * OO + o) * DD + d];
        const float sn = dred16(sv * sv);
        v = sv * (sn / ((1.0f + sn) * sqrtf(sn)));
        out[BB * DD + (b * OO + o) * DD + d] = v;
        if (d == 0) norml[o] = sn;  // argmax(softmax(sqrt(sn))) == argmax(sn)
    }
    __syncthreads();

    int idx = 0;
    float best = norml[0];
    #pragma unroll
    for (int oo = 1; oo < OO; oo++) {
        const float n = norml[oo];
        if (n > best) { best = n; idx = oo; }
    }
    if (o == idx) out[b * DD + d] = v;
}

extern "C" void kernel_launch(void* const* d_in, const int* in_sizes, int n_in,
                              void* d_out, int out_size, void* d_ws, size_t ws_size,
                              hipStream_t stream) {
    const float* x = (const float*)d_in[0];  // [512,1152,8]
    const float* W = (const float*)d_in[1];  // [10,1152,16,8]
    float* out = (float*)d_out;              // [512*16 t] ++ [512*10*16 outputs]

    float* s0 = (float*)d_ws;                // [512,10,16]
    float* s1 = s0 + BB * OO * DD;
    float* s2 = s1 + BB * OO * DD;

    hipMemsetAsync(d_ws, 0, (size_t)3 * BB * OO * DD * sizeof(float), stream);

    caps_pass<0><<<NBLK, 256, 0, stream>>>(x, W, s0, nullptr, nullptr);
    caps_pass<1><<<NBLK, 256, 0, stream>>>(x, W, s1, s0, nullptr);
    caps_pass<2><<<NBLK, 256, 0, stream>>>(x, W, s2, s0, s1);
    caps_final<<<BB, 192, 0, stream>>>(s2, out);
}